// Round 5
// baseline (231.136 us; speedup 1.0000x reference)
//
#include <hip/hip_runtime.h>

// LIF neuron scan over STEP=4 timesteps.
// x: [4, 64, 128, 32, 32] fp32; out same shape.
// Per element: mem = mem*0.25 + x_t; spike = mem > 0.5; mem *= (1-spike).
//
// R1/R3/R4 all compiled to <=24 VGPRs (compiler serialized loads:
// load -> vmcnt(0) -> store per step; sched_barrier(0) was ignored) and
// all landed at ~82 us = 3.3 TB/s effective, half the 6.3 TB/s copy
// ceiling. MLP-starved: ~2 KB in flight per wave.
//
// R5: force the pipeline with inline asm. 8 global_load_dwordx4 issued
// up front (8 KB in flight per wave), then per step: s_waitcnt vmcnt(6)
// (queue = 6 remaining loads + 2 younger stores -> retires exactly the
// two oldest loads; store-acks are never waited on), compute, store.
// Wait asm is tied to the guarded values ("+v") so compiler dataflow
// cannot hoist uses above the hardware wait; "memory" clobber pins the
// C stores into their inter-wait slot.

#define DECAY 0.25f

typedef float v4f __attribute__((ext_vector_type(4)));

__device__ __forceinline__ v4f lif_step(v4f& mem, const v4f xv) {
    mem = mem * DECAY + xv;                    // leaky integrate
    v4f s;
    s.x = mem.x > 0.5f ? 1.f : 0.f;
    s.y = mem.y > 0.5f ? 1.f : 0.f;
    s.z = mem.z > 0.5f ? 1.f : 0.f;
    s.w = mem.w > 0.5f ? 1.f : 0.f;
    mem.x = (s.x != 0.f) ? 0.f : mem.x;        // reset where spiked
    mem.y = (s.y != 0.f) ? 0.f : mem.y;
    mem.z = (s.z != 0.f) ? 0.f : mem.z;
    mem.w = (s.w != 0.f) ? 0.f : mem.w;
    return s;
}

#define LOAD16(dst, ptr) \
    asm volatile("global_load_dwordx4 %0, %1, off" : "=v"(dst) : "v"(ptr))

// Retires the two oldest outstanding vmem ops (the loads guarding ra/rb).
#define WAIT6(ra, rb) \
    asm volatile("s_waitcnt vmcnt(6)" : "+v"(ra), "+v"(rb) : : "memory")

__global__ __launch_bounds__(256) void lif_kernel(const v4f* __restrict__ x,
                                                  v4f* __restrict__ out,
                                                  int n4) {
    // Block owns 512 contiguous float4 granules; thread handles tid and
    // tid+256 so every access is stride-1 across the wave.
    int ia = blockIdx.x * 512 + threadIdx.x;
    int ib = ia + 256;
    if (ib >= n4) return;   // exact division in practice

    const v4f* pa0 = x + ia;
    const v4f* pb0 = x + ib;
    const v4f* pa1 = pa0 + n4;
    const v4f* pb1 = pb0 + n4;
    const v4f* pa2 = pa1 + n4;
    const v4f* pb2 = pb1 + n4;
    const v4f* pa3 = pa2 + n4;
    const v4f* pb3 = pb2 + n4;

    v4f a0, b0, a1, b1, a2, b2, a3, b3;
    LOAD16(a0, pa0);  LOAD16(b0, pb0);
    LOAD16(a1, pa1);  LOAD16(b1, pb1);
    LOAD16(a2, pa2);  LOAD16(b2, pb2);
    LOAD16(a3, pa3);  LOAD16(b3, pb3);

    v4f ma = (v4f)(0.f);
    v4f mb = (v4f)(0.f);

    WAIT6(a0, b0);
    out[ia]            = lif_step(ma, a0);
    out[ib]            = lif_step(mb, b0);
    WAIT6(a1, b1);
    out[n4 + ia]       = lif_step(ma, a1);
    out[n4 + ib]       = lif_step(mb, b1);
    WAIT6(a2, b2);
    out[2 * n4 + ia]   = lif_step(ma, a2);
    out[2 * n4 + ib]   = lif_step(mb, b2);
    WAIT6(a3, b3);
    out[3 * n4 + ia]   = lif_step(ma, a3);
    out[3 * n4 + ib]   = lif_step(mb, b3);
}

extern "C" void kernel_launch(void* const* d_in, const int* in_sizes, int n_in,
                              void* d_out, int out_size, void* d_ws, size_t ws_size,
                              hipStream_t stream) {
    const float* x = (const float*)d_in[0];
    float* out = (float*)d_out;

    int n = in_sizes[0];       // 4 * 64 * 128 * 32 * 32 = 33,554,432
    int n4 = n / 16;           // per-timestep float4 granule count = 2,097,152

    int block = 256;
    int grid = (n4 + 511) / 512;   // 4096 blocks, 512 granules per block

    lif_kernel<<<grid, block, 0, stream>>>((const v4f*)x, (v4f*)out, n4);
}